// Round 1
// baseline (209.468 us; speedup 1.0000x reference)
//
#include <hip/hip_runtime.h>

// GGCARAFE: gradient-guided CARAFE upsample, B=8, C=256, H=W=64, K=3, S=2
// ws layout (floats):
//   w1t  [256][64]          @ 0         (16384)   w1t[c*64+j]   = w1[j][c]
//   w2t  [576][36]          @ 16384     (20736)   w2t[jd*36+pq*9+kk] = w2[kk*4+pq][jd]
//   mean [B][H][W]          @ 37120     (32768)
//   comp [B][64][H][W]      @ 69888     (2097152)
//   mask [B][H][W][4][9]    @ 2167040   (1179648)  ([pq][kk] inner)
// total 3,346,688 floats = 13.4 MB

#define W1T_OFF   0
#define W2T_OFF   16384
#define MEAN_OFF  37120
#define COMP_OFF  69888
#define MASK_OFF  2167040

__global__ __launch_bounds__(256) void k_setup(const float* __restrict__ w1,
                                               const float* __restrict__ w2,
                                               float* __restrict__ ws) {
    float* w1t = ws + W1T_OFF;
    float* w2t = ws + W2T_OFF;
    int t = threadIdx.x;
    // w1: [64][256] (OIHW 1x1) -> w1t[c][j]
    for (int i = t; i < 64 * 256; i += 256) {
        int c = i >> 6, j = i & 63;
        w1t[i] = w1[j * 256 + c];
    }
    // w2: [36][64][3][3] -> w2t[j*9+dy*3+dx][pq*9+kk],  o = kk*4+pq
    for (int i = t; i < 576 * 36; i += 256) {
        int jd = i / 36;          // j*9 + dy*3 + dx
        int o2 = i % 36;          // pq*9 + kk
        int pq = o2 / 9, kk = o2 % 9;
        w2t[i] = w2[(kk * 4 + pq) * 576 + jd];
    }
}

// comp[b][j][hw] = b1[j] + sum_c w1[j][c] * x[b][c][hw];  mean[b][hw] = avg_c x
// grid 512: jg = blockIdx>>7 (4 groups of 16 j), pix = (blockIdx&127)*256 + tid
__global__ __launch_bounds__(256) void k_comp(const float* __restrict__ x,
                                              const float* __restrict__ b1,
                                              float* __restrict__ ws) {
    const float* w1t = ws + W1T_OFF;
    float* mean = ws + MEAN_OFF;
    float* comp = ws + COMP_OFF;
    int jg = blockIdx.x >> 7;                          // uniform
    int pix = ((blockIdx.x & 127) << 8) + threadIdx.x; // 0..32767
    int b = pix >> 12, hw = pix & 4095;
    const float* xp = x + (size_t)b * 256 * 4096 + hw;
    float acc[16];
#pragma unroll
    for (int jj = 0; jj < 16; jj++) acc[jj] = b1[jg * 16 + jj];
    float msum = 0.f;
    for (int c = 0; c < 256; c++) {
        float xv = xp[(size_t)c * 4096];
        msum += xv;
        const float* wp = w1t + c * 64 + jg * 16;   // uniform address -> s_load
#pragma unroll
        for (int jj = 0; jj < 16; jj++) acc[jj] += wp[jj] * xv;
    }
    float* cb = comp + (size_t)b * 64 * 4096 + hw;
#pragma unroll
    for (int jj = 0; jj < 16; jj++) cb[(size_t)(jg * 16 + jj) * 4096] = acc[jj];
    if (jg == 0) mean[pix] = msum * (1.f / 256.f);
}

// kern (3x3 conv on comp) + gradient guidance + softmax over kk -> mask
// grid 256: phalf = blockIdx>>7 (pq pairs {0,1} / {2,3}), pix = (blockIdx&127)*256+tid
__global__ __launch_bounds__(256) void k_mask(const float* __restrict__ b2,
                                              float* __restrict__ ws) {
    const float* w2t = ws + W2T_OFF;
    const float* mean = ws + MEAN_OFF;
    const float* comp = ws + COMP_OFF;
    float* mask = ws + MASK_OFF;
    int phalf = blockIdx.x >> 7;                       // uniform 0..1
    int pix = ((blockIdx.x & 127) << 8) + threadIdx.x;
    int b = pix >> 12, hw = pix & 4095, h = hw >> 6, w = hw & 63;

    float acc[2][9];
#pragma unroll
    for (int pp = 0; pp < 2; pp++)
#pragma unroll
        for (int kk = 0; kk < 9; kk++) acc[pp][kk] = b2[kk * 4 + phalf * 2 + pp];

    const float* cb = comp + (size_t)b * 64 * 4096;
    for (int j = 0; j < 64; j++) {
#pragma unroll
        for (int dy = 0; dy < 3; dy++) {
            int y = h + dy - 1;
            bool yok = (unsigned)y < 64u;
            float c0 = 0.f, c1 = 0.f, c2 = 0.f;
            if (yok) {
                const float* row = cb + (size_t)j * 4096 + y * 64 + w;
                c1 = row[0];
                if (w > 0) c0 = row[-1];
                if (w < 63) c2 = row[1];
            }
            // uniform address -> scalar loads
            const float* wp = w2t + (size_t)(j * 9 + dy * 3) * 36 + phalf * 18;
#pragma unroll
            for (int pp = 0; pp < 2; pp++)
#pragma unroll
                for (int kk = 0; kk < 9; kk++) {
                    int oo = pp * 9 + kk;
                    acc[pp][kk] += wp[oo] * c0 + wp[36 + oo] * c1 + wp[72 + oo] * c2;
                }
        }
    }

    // gradient guidance from mean patch
    float mc = mean[pix];
    float g[9];
#pragma unroll
    for (int kk = 0; kk < 9; kk++) {
        int y = h + kk / 3 - 1, xw = w + kk % 3 - 1;
        float mv = ((unsigned)y < 64u && (unsigned)xw < 64u)
                       ? mean[(b * 64 + y) * 64 + xw] : 0.f;
        float d = mv - mc;
        g[kk] = 1.f / (d * d + 0.2f);
    }

    float* mout = mask + (size_t)pix * 36 + phalf * 18;
#pragma unroll
    for (int pp = 0; pp < 2; pp++) {
        float v[9], mx = -1e30f;
#pragma unroll
        for (int kk = 0; kk < 9; kk++) {
            v[kk] = g[kk] * acc[pp][kk];
            mx = fmaxf(mx, v[kk]);
        }
        float s = 0.f;
#pragma unroll
        for (int kk = 0; kk < 9; kk++) {
            v[kk] = __expf(v[kk] - mx);
            s += v[kk];
        }
        float inv = 1.f / s;
#pragma unroll
        for (int kk = 0; kk < 9; kk++) mout[pp * 9 + kk] = v[kk] * inv;
    }
}

// out[b][c][2h+p][2w+q] = sum_kk x[b][c][h+dy-1][w+dx-1] * mask[b][h][w][p*2+q][kk]
// grid 512 = (b,h); threads: ow = t&127 (output column), cslot = t>>7
__global__ __launch_bounds__(256) void k_out(const float* __restrict__ x,
                                             const float* __restrict__ ws,
                                             float* __restrict__ out) {
    const float* mask = ws + MASK_OFF;
    int bh = blockIdx.x;
    int b = bh >> 6, h = bh & 63;
    int t = threadIdx.x;
    int ow = t & 127, cslot = t >> 7;
    int w = ow >> 1, q = ow & 1;

    const float* mrow = mask + (size_t)((b * 64 + h) * 64 + w) * 36;
    float m0[9], m1[9];
#pragma unroll
    for (int kk = 0; kk < 9; kk++) {
        m0[kk] = mrow[q * 9 + kk];        // p=0 -> pq=q
        m1[kk] = mrow[(2 + q) * 9 + kk];  // p=1 -> pq=2+q
    }

    for (int c = cslot; c < 256; c += 2) {
        const float* xb = x + (size_t)(b * 256 + c) * 4096;
        float p[3][3];
#pragma unroll
        for (int dy = 0; dy < 3; dy++) {
            int y = h + dy - 1;
            bool yok = (unsigned)y < 64u;
#pragma unroll
            for (int dx = 0; dx < 3; dx++) {
                int xx = w + dx - 1;
                p[dy][dx] = (yok && (unsigned)xx < 64u) ? xb[y * 64 + xx] : 0.f;
            }
        }
        float o0 = 0.f, o1 = 0.f;
#pragma unroll
        for (int kk = 0; kk < 9; kk++) {
            float pv = p[kk / 3][kk % 3];
            o0 += pv * m0[kk];
            o1 += pv * m1[kk];
        }
        float* ob = out + ((size_t)(b * 256 + c) * 128 + 2 * h) * 128 + ow;
        ob[0] = o0;     // p=0 row
        ob[128] = o1;   // p=1 row
    }
}

extern "C" void kernel_launch(void* const* d_in, const int* in_sizes, int n_in,
                              void* d_out, int out_size, void* d_ws, size_t ws_size,
                              hipStream_t stream) {
    const float* x  = (const float*)d_in[0];
    const float* w1 = (const float*)d_in[1];
    const float* b1 = (const float*)d_in[2];
    const float* w2 = (const float*)d_in[3];
    const float* b2 = (const float*)d_in[4];
    float* out = (float*)d_out;
    float* ws  = (float*)d_ws;

    k_setup<<<1, 256, 0, stream>>>(w1, w2, ws);
    k_comp<<<512, 256, 0, stream>>>(x, b1, ws);
    k_mask<<<256, 256, 0, stream>>>(b2, ws);
    k_out<<<512, 256, 0, stream>>>(x, ws, out);
}